// Round 1
// baseline (2928.888 us; speedup 1.0000x reference)
//
#include <hip/hip_runtime.h>
#include <cstddef>
#include <cstdint>

// Problem constants (fixed by setup_inputs)
#define T_   8
#define N_   10000
#define E_   320000
#define F_   128
#define D1_  128
#define D2_  64
#define DR_  128     // d_rnn
#define DD_  64      // d_dec
#define NC_  100     // communities
#define TN_  (T_*N_)
#define TE_  (T_*E_)

// ---------------------------------------------------------------------------
// Generic fp32 GEMM: C[M x Nc] = A[M x K] @ B[K x Nc] (+bias) (+=C) (act)
// 64x64 tile, 256 threads, 4x4 per thread, BK=16. K % 16 == 0, Nc % 64 == 0.
// act: 0 none, 1 tanh, 2 sigmoid
// ---------------------------------------------------------------------------
__global__ __launch_bounds__(256) void gemm_f32(
    const float* __restrict__ A, const float* __restrict__ B, float* __restrict__ C,
    const float* __restrict__ bias, int M, int K, int Nc, int accum, int act)
{
    __shared__ float As[16][68];   // As[k][m] (transposed)
    __shared__ float Bs[16][68];   // Bs[k][n]
    int tid = threadIdx.x;
    int tx = tid & 15, ty = tid >> 4;
    int bm = blockIdx.y * 64, bn = blockIdx.x * 64;
    float acc[4][4] = {{0.f}};
    int ar = tid >> 2, ak = (tid & 3) * 4;   // A tile load: row ar, k-offset ak
    int bk = tid >> 4, bj = (tid & 15) * 4;  // B tile load: k bk, col bj

    for (int k0 = 0; k0 < K; k0 += 16) {
        float4 av = make_float4(0.f, 0.f, 0.f, 0.f);
        if (bm + ar < M)
            av = *(const float4*)(A + (size_t)(bm + ar) * K + k0 + ak);
        As[ak + 0][ar] = av.x; As[ak + 1][ar] = av.y;
        As[ak + 2][ar] = av.z; As[ak + 3][ar] = av.w;
        float4 bv = *(const float4*)(B + (size_t)(k0 + bk) * Nc + bn + bj);
        *(float4*)(&Bs[bk][bj]) = bv;
        __syncthreads();
        #pragma unroll
        for (int kk = 0; kk < 16; ++kk) {
            float4 a = *(const float4*)&As[kk][ty * 4];
            float4 b = *(const float4*)&Bs[kk][tx * 4];
            acc[0][0] += a.x*b.x; acc[0][1] += a.x*b.y; acc[0][2] += a.x*b.z; acc[0][3] += a.x*b.w;
            acc[1][0] += a.y*b.x; acc[1][1] += a.y*b.y; acc[1][2] += a.y*b.z; acc[1][3] += a.y*b.w;
            acc[2][0] += a.z*b.x; acc[2][1] += a.z*b.y; acc[2][2] += a.z*b.z; acc[2][3] += a.z*b.w;
            acc[3][0] += a.w*b.x; acc[3][1] += a.w*b.y; acc[3][2] += a.w*b.z; acc[3][3] += a.w*b.w;
        }
        __syncthreads();
    }

    int col = bn + tx * 4;
    #pragma unroll
    for (int i = 0; i < 4; ++i) {
        int row = bm + ty * 4 + i;
        if (row >= M) continue;
        float* cp = C + (size_t)row * Nc + col;
        float v0 = acc[i][0], v1 = acc[i][1], v2 = acc[i][2], v3 = acc[i][3];
        if (bias) { v0 += bias[col]; v1 += bias[col+1]; v2 += bias[col+2]; v3 += bias[col+3]; }
        if (accum) {
            float4 c0 = *(const float4*)cp;
            v0 += c0.x; v1 += c0.y; v2 += c0.z; v3 += c0.w;
        }
        if (act == 1) { v0 = tanhf(v0); v1 = tanhf(v1); v2 = tanhf(v2); v3 = tanhf(v3); }
        else if (act == 2) {
            v0 = 1.f/(1.f+expf(-v0)); v1 = 1.f/(1.f+expf(-v1));
            v2 = 1.f/(1.f+expf(-v2)); v3 = 1.f/(1.f+expf(-v3));
        }
        *(float4*)cp = make_float4(v0, v1, v2, v3);
    }
}

// ---------------------------------------------------------------------------
// Per-node attention vectors: as[n,h] = dot(h[n, h*dh : (h+1)*dh], a_src[h]),
// same for ad. One wave per row.
// ---------------------------------------------------------------------------
__global__ __launch_bounds__(256) void att_vec128(
    const float* __restrict__ h, const float* __restrict__ a_src,
    const float* __restrict__ a_dst, float* __restrict__ as_out,
    float* __restrict__ ad_out, int rows)
{
    int wid  = (blockIdx.x * 256 + threadIdx.x) >> 6;
    int lane = threadIdx.x & 63;
    if (wid >= rows) return;
    const float* hr = h + (size_t)wid * 128;
    float v0 = hr[lane], v1 = hr[64 + lane];
    float pa0 = v0 * a_src[lane], pa1 = v1 * a_src[64 + lane];
    float pd0 = v0 * a_dst[lane], pd1 = v1 * a_dst[64 + lane];
    #pragma unroll
    for (int m = 1; m <= 16; m <<= 1) {
        pa0 += __shfl_xor(pa0, m); pa1 += __shfl_xor(pa1, m);
        pd0 += __shfl_xor(pd0, m); pd1 += __shfl_xor(pd1, m);
    }
    if ((lane & 31) == 0) {
        int g = lane >> 5;  // dims [0,32) -> head0, [32,64) -> head1, etc.
        as_out[wid * 4 + g]     = pa0; as_out[wid * 4 + 2 + g] = pa1;
        ad_out[wid * 4 + g]     = pd0; ad_out[wid * 4 + 2 + g] = pd1;
    }
}

__global__ __launch_bounds__(256) void att_vec64(
    const float* __restrict__ h, const float* __restrict__ a_src,
    const float* __restrict__ a_dst, float* __restrict__ as_out,
    float* __restrict__ ad_out, int rows)
{
    int wid  = (blockIdx.x * 256 + threadIdx.x) >> 6;
    int lane = threadIdx.x & 63;
    if (wid >= rows) return;
    float v = h[(size_t)wid * 64 + lane];
    float pa = v * a_src[lane], pd = v * a_dst[lane];
    #pragma unroll
    for (int m = 1; m <= 8; m <<= 1) { pa += __shfl_xor(pa, m); pd += __shfl_xor(pd, m); }
    if ((lane & 15) == 0) {
        int g = lane >> 4;
        as_out[wid * 4 + g] = pa; ad_out[wid * 4 + g] = pd;
    }
}

// ---------------------------------------------------------------------------
// CSR build over dst (per timestep t, global row index = t*N + node)
// ---------------------------------------------------------------------------
__global__ void count_edges(const int* __restrict__ eidx, int* __restrict__ counts)
{
    int idx = blockIdx.x * 256 + threadIdx.x;
    if (idx >= TE_) return;
    int t = idx / E_, e = idx - t * E_;
    int d = eidx[(size_t)t * 2 * E_ + E_ + e];
    atomicAdd(&counts[t * N_ + d], 1);
}

__global__ __launch_bounds__(1024) void scan_per_t(
    const int* __restrict__ counts, int* __restrict__ rowptr, int* __restrict__ cursor)
{
    const int CH = 10;  // 1024*10 >= 10000
    int t = blockIdx.x, i = threadIdx.x;
    int base0 = t * N_;
    int cnt[CH];
    int s = 0;
    int g0 = i * CH;
    #pragma unroll
    for (int q = 0; q < CH; ++q) {
        int g = g0 + q;
        cnt[q] = (g < N_) ? counts[base0 + g] : 0;
        s += cnt[q];
    }
    __shared__ int buf[1024];
    buf[i] = s;
    __syncthreads();
    for (int off = 1; off < 1024; off <<= 1) {
        int v = (i >= off) ? buf[i - off] : 0;
        __syncthreads();
        buf[i] += v;
        __syncthreads();
    }
    int run = t * E_ + buf[i] - s;  // exclusive prefix + per-t base
    #pragma unroll
    for (int q = 0; q < CH; ++q) {
        int g = g0 + q;
        if (g < N_) {
            rowptr[base0 + g] = run;
            cursor[base0 + g] = run;
            run += cnt[q];
        }
    }
    if (t == T_ - 1 && i == 1023) rowptr[T_ * N_] = TE_;
}

__global__ void fill_csr(const int* __restrict__ eidx, const float* __restrict__ ew,
                         int* __restrict__ cursor, int* __restrict__ src_csr,
                         float* __restrict__ ew_csr)
{
    int idx = blockIdx.x * 256 + threadIdx.x;
    if (idx >= TE_) return;
    int t = idx / E_, e = idx - t * E_;
    int s = eidx[(size_t)t * 2 * E_ + e];
    int d = eidx[(size_t)t * 2 * E_ + E_ + e];
    float w = ew[(size_t)t * E_ + e];
    int pos = atomicAdd(&cursor[t * N_ + d], 1);
    src_csr[pos] = t * N_ + s;   // store GLOBAL src row
    ew_csr[pos] = w;
}

// ---------------------------------------------------------------------------
// GAT aggregation, d=128 (H=4, dh=32). One wave per dst node; lane owns dims
// {lane, lane+64} belonging to heads {lane>>5, 2+(lane>>5)}.
// ---------------------------------------------------------------------------
__global__ __launch_bounds__(256) void gat_node_128(
    const float* __restrict__ h, const float* __restrict__ as,
    const float* __restrict__ ad, const int* __restrict__ rowptr,
    const int* __restrict__ src_csr, const float* __restrict__ ew_csr,
    float* __restrict__ outp, int rows)
{
    int wid  = (blockIdx.x * 256 + threadIdx.x) >> 6;
    int lane = threadIdx.x & 63;
    if (wid >= rows) return;
    int start = rowptr[wid], end = rowptr[wid + 1];
    int h0 = lane >> 5, h1 = 2 + h0;
    float ad0 = ad[wid * 4 + h0], ad1 = ad[wid * 4 + h1];
    float mx0 = -INFINITY, mx1 = -INFINITY;
    for (int p = start; p < end; ++p) {
        int s = src_csr[p];
        float e0 = as[s * 4 + h0] + ad0; e0 = e0 > 0.f ? e0 : 0.2f * e0;
        float e1 = as[s * 4 + h1] + ad1; e1 = e1 > 0.f ? e1 : 0.2f * e1;
        mx0 = fmaxf(mx0, e0); mx1 = fmaxf(mx1, e1);
    }
    float acc0 = 0.f, acc1 = 0.f, den0 = 0.f, den1 = 0.f;
    for (int p = start; p < end; ++p) {
        int s = src_csr[p];
        float w = ew_csr[p];
        float e0 = as[s * 4 + h0] + ad0; e0 = e0 > 0.f ? e0 : 0.2f * e0;
        float e1 = as[s * 4 + h1] + ad1; e1 = e1 > 0.f ? e1 : 0.2f * e1;
        float x0 = __expf(e0 - mx0) * w;
        float x1 = __expf(e1 - mx1) * w;
        den0 += x0; den1 += x1;
        const float* hs = h + (size_t)s * 128;
        acc0 += x0 * hs[lane];
        acc1 += x1 * hs[64 + lane];
    }
    float o0 = acc0 / (den0 + 1e-16f);
    float o1 = acc1 / (den1 + 1e-16f);
    o0 = o0 > 0.f ? o0 : (expf(o0) - 1.f);   // ELU
    o1 = o1 > 0.f ? o1 : (expf(o1) - 1.f);
    outp[(size_t)wid * 128 + lane]      = o0;
    outp[(size_t)wid * 128 + 64 + lane] = o1;
}

// GAT aggregation, d=64 (H=4, dh=16). Lane owns dim=lane, head=lane>>4.
__global__ __launch_bounds__(256) void gat_node_64(
    const float* __restrict__ h, const float* __restrict__ as,
    const float* __restrict__ ad, const int* __restrict__ rowptr,
    const int* __restrict__ src_csr, const float* __restrict__ ew_csr,
    float* __restrict__ outp, int rows)
{
    int wid  = (blockIdx.x * 256 + threadIdx.x) >> 6;
    int lane = threadIdx.x & 63;
    if (wid >= rows) return;
    int start = rowptr[wid], end = rowptr[wid + 1];
    int hh = lane >> 4;
    float adv = ad[wid * 4 + hh];
    float mx = -INFINITY;
    for (int p = start; p < end; ++p) {
        int s = src_csr[p];
        float e = as[s * 4 + hh] + adv; e = e > 0.f ? e : 0.2f * e;
        mx = fmaxf(mx, e);
    }
    float acc = 0.f, den = 0.f;
    for (int p = start; p < end; ++p) {
        int s = src_csr[p];
        float w = ew_csr[p];
        float e = as[s * 4 + hh] + adv; e = e > 0.f ? e : 0.2f * e;
        float x = __expf(e - mx) * w;
        den += x;
        acc += x * h[(size_t)s * 64 + lane];
    }
    float o = acc / (den + 1e-16f);
    o = o > 0.f ? o : (expf(o) - 1.f);
    outp[(size_t)wid * 64 + lane] = o;
}

// ---------------------------------------------------------------------------
// Meso pooling: weighted mean per (t, community). One wave per node row.
// ---------------------------------------------------------------------------
__global__ __launch_bounds__(256) void meso_acc(
    const float* __restrict__ g2, const int* __restrict__ part,
    const float* __restrict__ Dw, float* __restrict__ msum, float* __restrict__ mden)
{
    int wid  = (blockIdx.x * 256 + threadIdx.x) >> 6;
    int lane = threadIdx.x & 63;
    if (wid >= TN_) return;
    int t = wid / N_;
    int p = part[wid];
    float dv = Dw[wid];
    atomicAdd(&msum[((size_t)(t * NC_ + p) << 6) + lane], dv * g2[(size_t)wid * 64 + lane]);
    if (lane == 0) atomicAdd(&mden[t * NC_ + p], dv);
}

__global__ void agg_assemble(
    const float* __restrict__ g2, const int* __restrict__ part,
    const float* __restrict__ msum, const float* __restrict__ mden,
    float* __restrict__ agg)
{
    int idx = blockIdx.x * 256 + threadIdx.x;   // < TN*128
    int row = idx >> 7, d = idx & 127;
    float v;
    if (d < 64) {
        v = g2[(size_t)row * 64 + d];
    } else {
        int t = row / N_;
        int p = part[row];
        v = msum[((size_t)(t * NC_ + p) << 6) + (d - 64)] / (mden[t * NC_ + p] + 1e-16f);
    }
    agg[idx] = v;
}

// ---------------------------------------------------------------------------
// LSTM cell elementwise. z layout per row: [i(128) f(128) g(128) o(128)].
// ---------------------------------------------------------------------------
__global__ void lstm_cell(const float* __restrict__ z, float* __restrict__ h,
                          float* __restrict__ c)
{
    int idx = blockIdx.x * 256 + threadIdx.x;   // < N*128
    int n = idx >> 7, j = idx & 127;
    const float* zr = z + (size_t)n * 512;
    float zi = zr[j], zf = zr[128 + j], zg = zr[256 + j], zo = zr[384 + j];
    float si = 1.f / (1.f + expf(-zi));
    float sf = 1.f / (1.f + expf(-zf));
    float so = 1.f / (1.f + expf(-zo));
    float cn = sf * c[idx] + si * tanhf(zg);
    c[idx] = cn;
    h[idx] = so * tanhf(cn);
}

// ---------------------------------------------------------------------------
// Column sum-of-squares for emb (10000 x 64), coalesced, block-partial + atomic
// ---------------------------------------------------------------------------
__global__ __launch_bounds__(256) void col_sumsq(const float* __restrict__ emb,
                                                 float* __restrict__ colss)
{
    int tid = threadIdx.x;
    int col = tid & 63, rq = tid >> 6;
    float s = 0.f;
    for (int r = blockIdx.x * 4 + rq; r < N_; r += 40 * 4) {
        float v = emb[(size_t)r * 64 + col];
        s += v * v;
    }
    __shared__ float red[256];
    red[tid] = s;
    __syncthreads();
    if (tid < 64)
        atomicAdd(&colss[tid], red[tid] + red[tid + 64] + red[tid + 128] + red[tid + 192]);
}

// Normalize emb columns by sqrt(colss); compute per-row sumsq -> sq[row].
__global__ __launch_bounds__(256) void norm_rows(float* __restrict__ emb,
                                                 const float* __restrict__ colss,
                                                 float* __restrict__ sq, int rows)
{
    int wid  = (blockIdx.x * 256 + threadIdx.x) >> 6;
    int lane = threadIdx.x & 63;
    if (wid >= rows) return;
    float nv = emb[(size_t)wid * 64 + lane] / sqrtf(colss[lane]);
    emb[(size_t)wid * 64 + lane] = nv;
    float q = nv * nv;
    #pragma unroll
    for (int m = 1; m <= 32; m <<= 1) q += __shfl_xor(q, m);
    if (lane == 0) sq[wid] = q;
}

// ---------------------------------------------------------------------------
// Fused final: S = scal.scal^T, G = emb.emb^T, dist = -(sq_i+sq_j-2G),
// out = 1 + tanh(dist*S). 64x64 tile, K=64 per matrix chunked by 16 in LDS.
// ---------------------------------------------------------------------------
__global__ __launch_bounds__(256) void final_adj(
    const float* __restrict__ emb, const float* __restrict__ scal,
    const float* __restrict__ sq, float* __restrict__ outp)
{
    __shared__ float sI[16][68], gI[16][68], sJ[16][68], gJ[16][68];
    int tid = threadIdx.x;
    int tx = tid & 15, ty = tid >> 4;
    int bi = blockIdx.y * 64, bj = blockIdx.x * 64;
    float accS[4][4] = {{0.f}}, accG[4][4] = {{0.f}};
    int lr = tid >> 2, lk = (tid & 3) * 4;
    int ri = bi + lr, rj = bj + lr;
    const float4 z4 = make_float4(0.f, 0.f, 0.f, 0.f);

    for (int k0 = 0; k0 < 64; k0 += 16) {
        float4 v;
        v = (ri < N_) ? *(const float4*)(scal + (size_t)ri * 64 + k0 + lk) : z4;
        sI[lk+0][lr] = v.x; sI[lk+1][lr] = v.y; sI[lk+2][lr] = v.z; sI[lk+3][lr] = v.w;
        v = (ri < N_) ? *(const float4*)(emb + (size_t)ri * 64 + k0 + lk) : z4;
        gI[lk+0][lr] = v.x; gI[lk+1][lr] = v.y; gI[lk+2][lr] = v.z; gI[lk+3][lr] = v.w;
        v = (rj < N_) ? *(const float4*)(scal + (size_t)rj * 64 + k0 + lk) : z4;
        sJ[lk+0][lr] = v.x; sJ[lk+1][lr] = v.y; sJ[lk+2][lr] = v.z; sJ[lk+3][lr] = v.w;
        v = (rj < N_) ? *(const float4*)(emb + (size_t)rj * 64 + k0 + lk) : z4;
        gJ[lk+0][lr] = v.x; gJ[lk+1][lr] = v.y; gJ[lk+2][lr] = v.z; gJ[lk+3][lr] = v.w;
        __syncthreads();
        #pragma unroll
        for (int kk = 0; kk < 16; ++kk) {
            float4 a = *(const float4*)&sI[kk][ty * 4];
            float4 b = *(const float4*)&sJ[kk][tx * 4];
            float4 c = *(const float4*)&gI[kk][ty * 4];
            float4 d = *(const float4*)&gJ[kk][tx * 4];
            accS[0][0] += a.x*b.x; accS[0][1] += a.x*b.y; accS[0][2] += a.x*b.z; accS[0][3] += a.x*b.w;
            accS[1][0] += a.y*b.x; accS[1][1] += a.y*b.y; accS[1][2] += a.y*b.z; accS[1][3] += a.y*b.w;
            accS[2][0] += a.z*b.x; accS[2][1] += a.z*b.y; accS[2][2] += a.z*b.z; accS[2][3] += a.z*b.w;
            accS[3][0] += a.w*b.x; accS[3][1] += a.w*b.y; accS[3][2] += a.w*b.z; accS[3][3] += a.w*b.w;
            accG[0][0] += c.x*d.x; accG[0][1] += c.x*d.y; accG[0][2] += c.x*d.z; accG[0][3] += c.x*d.w;
            accG[1][0] += c.y*d.x; accG[1][1] += c.y*d.y; accG[1][2] += c.y*d.z; accG[1][3] += c.y*d.w;
            accG[2][0] += c.z*d.x; accG[2][1] += c.z*d.y; accG[2][2] += c.z*d.z; accG[2][3] += c.z*d.w;
            accG[3][0] += c.w*d.x; accG[3][1] += c.w*d.y; accG[3][2] += c.w*d.z; accG[3][3] += c.w*d.w;
        }
        __syncthreads();
    }

    float sqi[4], sqj[4];
    #pragma unroll
    for (int i = 0; i < 4; ++i) { int r = bi + ty * 4 + i; sqi[i] = (r < N_) ? sq[r] : 0.f; }
    #pragma unroll
    for (int j = 0; j < 4; ++j) { int c = bj + tx * 4 + j; sqj[j] = (c < N_) ? sq[c] : 0.f; }

    #pragma unroll
    for (int i = 0; i < 4; ++i) {
        int r = bi + ty * 4 + i;
        if (r >= N_) continue;
        int c0 = bj + tx * 4;
        float vals[4];
        #pragma unroll
        for (int j = 0; j < 4; ++j) {
            float dist = -(sqi[i] + sqj[j] - 2.f * accG[i][j]);
            vals[j] = 1.f + tanhf(dist * accS[i][j]);
        }
        float* op = outp + (size_t)r * N_ + c0;
        if (c0 + 3 < N_) {
            *(float4*)op = make_float4(vals[0], vals[1], vals[2], vals[3]);
        } else {
            for (int j = 0; j < 4; ++j) if (c0 + j < N_) op[j] = vals[j];
        }
    }
}

// ---------------------------------------------------------------------------
extern "C" void kernel_launch(void* const* d_in, const int* in_sizes, int n_in,
                              void* d_out, int out_size, void* d_ws, size_t ws_size,
                              hipStream_t stream)
{
    (void)in_sizes; (void)n_in; (void)out_size; (void)ws_size;
    const float* feat    = (const float*)d_in[0];
    const float* eweight = (const float*)d_in[1];
    const float* Dw      = (const float*)d_in[2];
    const float* W1      = (const float*)d_in[3];
    const float* a_src1  = (const float*)d_in[4];
    const float* a_dst1  = (const float*)d_in[5];
    const float* W2      = (const float*)d_in[6];
    const float* a_src2  = (const float*)d_in[7];
    const float* a_dst2  = (const float*)d_in[8];
    const float* Wx      = (const float*)d_in[9];
    const float* Wh      = (const float*)d_in[10];
    const float* b_lstm  = (const float*)d_in[11];
    const float* emb_W   = (const float*)d_in[12];
    const float* emb_b   = (const float*)d_in[13];
    const float* scal_W  = (const float*)d_in[14];
    const float* scal_b  = (const float*)d_in[15];
    const int*   eidx    = (const int*)d_in[16];
    const int*   part    = (const int*)d_in[17];

    // Scratch layout: big dead-before-final buffers live inside d_out (1e8 floats,
    // fully overwritten by final_adj). Live-at-final buffers (emb/scal/sq/colss)
    // live in d_ws.
    float* out = (float*)d_out;
    float* h1     = out + 0;          // TN*128 (later reused as agg)
    float* g1     = out + 10240000;   // TN*128 (later reused as zbuf)
    float* h2     = out + 20480000;   // TN*64
    float* g2     = out + 25600000;   // TN*64
    float* as1    = out + 30720000;   // TN*4
    float* ad1    = out + 31040000;
    float* as2    = out + 31360000;
    float* ad2    = out + 31680000;
    int*   rowptr = (int*)(out + 32000000);  // TN+1
    int*   cursor = (int*)(out + 32080064);  // TN
    int*   counts = (int*)(out + 32160064);  // TN
    int*   src_csr= (int*)(out + 32240064);  // TE
    float* ew_csr = out + 34800064;          // TE
    float* msum   = out + 37360064;          // T*100*64
    float* mden   = out + 37411264;          // T*100
    float* hstate = out + 37412064;          // N*128
    float* cstate = out + 38692064;          // N*128  (ends 39,972,064 < 1e8)

    float* emb   = (float*)d_ws;             // N*64
    float* scal  = emb + 640000;             // N*64
    float* sq    = emb + 1280000;            // N
    float* colss = emb + 1290000;            // 64

    // Zero-init what gets accumulated into
    hipMemsetAsync(counts, 0, TN_ * sizeof(int), stream);
    hipMemsetAsync(msum, 0, (T_ * NC_ * 64 + T_ * NC_) * sizeof(float), stream);
    hipMemsetAsync(hstate, 0, 2 * N_ * DR_ * sizeof(float), stream);
    hipMemsetAsync(colss, 0, 64 * sizeof(float), stream);

    // ---- GAT layer 1 (batched over all T) ----
    gemm_f32<<<dim3(D1_/64, TN_/64), 256, 0, stream>>>(feat, W1, h1, nullptr, TN_, F_, D1_, 0, 0);
    att_vec128<<<TN_/4, 256, 0, stream>>>(h1, a_src1, a_dst1, as1, ad1, TN_);
    count_edges<<<(TE_+255)/256, 256, 0, stream>>>(eidx, counts);
    scan_per_t<<<T_, 1024, 0, stream>>>(counts, rowptr, cursor);
    fill_csr<<<(TE_+255)/256, 256, 0, stream>>>(eidx, eweight, cursor, src_csr, ew_csr);
    gat_node_128<<<TN_/4, 256, 0, stream>>>(h1, as1, ad1, rowptr, src_csr, ew_csr, g1, TN_);

    // ---- GAT layer 2 ----
    gemm_f32<<<dim3(D2_/64, TN_/64), 256, 0, stream>>>(g1, W2, h2, nullptr, TN_, D1_, D2_, 0, 0);
    att_vec64<<<TN_/4, 256, 0, stream>>>(h2, a_src2, a_dst2, as2, ad2, TN_);
    gat_node_64<<<TN_/4, 256, 0, stream>>>(h2, as2, ad2, rowptr, src_csr, ew_csr, g2, TN_);

    // ---- meso pooling + agg assembly ----
    meso_acc<<<TN_/4, 256, 0, stream>>>(g2, part, Dw, msum, mden);
    float* agg = h1;   // h1 dead after gat_node_128
    agg_assemble<<<TN_*128/256, 256, 0, stream>>>(g2, part, msum, mden, agg);

    // ---- LSTM over T steps ----
    float* zbuf = g1;  // g1 dead after GAT2 projection
    for (int t = 0; t < T_; ++t) {
        gemm_f32<<<dim3(512/64, (N_+63)/64), 256, 0, stream>>>(
            agg + (size_t)t * N_ * 128, Wx, zbuf, b_lstm, N_, 128, 512, 0, 0);
        gemm_f32<<<dim3(512/64, (N_+63)/64), 256, 0, stream>>>(
            hstate, Wh, zbuf, nullptr, N_, 128, 512, 1, 0);
        lstm_cell<<<N_*DR_/256, 256, 0, stream>>>(zbuf, hstate, cstate);
    }

    // ---- decoder heads ----
    gemm_f32<<<dim3(1, (N_+63)/64), 256, 0, stream>>>(hstate, emb_W, emb, emb_b, N_, 128, 64, 0, 1);
    gemm_f32<<<dim3(1, (N_+63)/64), 256, 0, stream>>>(hstate, scal_W, scal, scal_b, N_, 128, 64, 0, 2);
    col_sumsq<<<40, 256, 0, stream>>>(emb, colss);
    norm_rows<<<(N_+3)/4, 256, 0, stream>>>(emb, colss, sq, N_);

    // ---- fused S/G/dist/adj ----
    final_adj<<<dim3((N_+63)/64, (N_+63)/64), 256, 0, stream>>>(emb, scal, sq, out);
}

// Round 2
// 2092.946 us; speedup vs baseline: 1.3994x; 1.3994x over previous
//
#include <hip/hip_runtime.h>
#include <cstddef>
#include <cstdint>

// Problem constants (fixed by setup_inputs)
#define T_   8
#define N_   10000
#define E_   320000
#define F_   128
#define D1_  128
#define D2_  64
#define DR_  128
#define NC_  100
#define TN_  (T_*N_)
#define TE_  (T_*E_)
#define NPAD_ 10112   // 79*128, row padding for M=10000 MFMA tiles

typedef __attribute__((ext_vector_type(8))) short bf16x8;
typedef __attribute__((ext_vector_type(8))) ushort u16x8;
typedef __attribute__((ext_vector_type(4))) float f32x4;

__device__ __forceinline__ float bf2f(ushort u) {
    return __uint_as_float(((unsigned int)u) << 16);
}
__device__ __forceinline__ ushort f2bf(float f) {
    unsigned int u = __float_as_uint(f);
    unsigned int r = (u + 0x7FFFu + ((u >> 16) & 1u)) >> 16;   // RNE
    return (ushort)r;
}
// numerically safe fast tanh / sigmoid (inf-safe forms)
__device__ __forceinline__ float fast_tanh(float x) {
    float t = __expf(2.f * x);
    return 1.f - 2.f / (t + 1.f);
}
__device__ __forceinline__ float fast_sigmoid(float x) {
    return 1.f / (1.f + __expf(-x));
}

// ---------------------------------------------------------------------------
// fp32 -> bf16 bulk convert (feat). 8 elems/thread.
// ---------------------------------------------------------------------------
__global__ __launch_bounds__(256) void conv_feat(const float* __restrict__ src,
                                                 ushort* __restrict__ dst, int n8)
{
    int idx = blockIdx.x * 256 + threadIdx.x;
    if (idx >= n8) return;
    const float4* s = (const float4*)src + (size_t)idx * 2;
    float4 x = s[0], y = s[1];
    u16x8 o;
    o[0]=f2bf(x.x); o[1]=f2bf(x.y); o[2]=f2bf(x.z); o[3]=f2bf(x.w);
    o[4]=f2bf(y.x); o[5]=f2bf(y.y); o[6]=f2bf(y.z); o[7]=f2bf(y.w);
    *((u16x8*)dst + idx) = o;
}

// ---------------------------------------------------------------------------
// All weights -> transposed bf16 (BT[n][k] = W[k][n]) in one launch.
// Segments: W1 128x128, W2 128x64, Wx 128x512, Wh 128x512, eW 128x64, sW 128x64
// ---------------------------------------------------------------------------
__global__ __launch_bounds__(256) void conv_weights(
    const float* __restrict__ W1, const float* __restrict__ W2,
    const float* __restrict__ Wx, const float* __restrict__ Wh,
    const float* __restrict__ eW, const float* __restrict__ sW,
    ushort* __restrict__ W1T, ushort* __restrict__ W2T,
    ushort* __restrict__ WxT, ushort* __restrict__ WhT,
    ushort* __restrict__ eWT, ushort* __restrict__ sWT)
{
    int idx = blockIdx.x * 256 + threadIdx.x;
    if (idx < 16384)       { int n=idx>>7,   k=idx&127;            W1T[idx]=f2bf(W1[k*128+n]); }
    else if (idx < 24576)  { int l=idx-16384;  int n=l>>7,k=l&127; W2T[l]=f2bf(W2[k*64+n]); }
    else if (idx < 90112)  { int l=idx-24576;  int n=l>>7,k=l&127; WxT[l]=f2bf(Wx[k*512+n]); }
    else if (idx < 155648) { int l=idx-90112;  int n=l>>7,k=l&127; WhT[l]=f2bf(Wh[k*512+n]); }
    else if (idx < 163840) { int l=idx-155648; int n=l>>7,k=l&127; eWT[l]=f2bf(eW[k*64+n]); }
    else if (idx < 172032) { int l=idx-163840; int n=l>>7,k=l&127; sWT[l]=f2bf(sW[k*64+n]); }
}

// ---------------------------------------------------------------------------
// bf16 MFMA GEMM: C[M x Nc] = A[M x K] @ BT[Nc x K]^T  (+bias) (+addsrc) (act)
// K % 32 == 0, Nc % 64 == 0. Block 256 thr = 4 waves; tile 128 x 64; each wave
// computes 32 x 64 (2x4 tiles of 16x16, mfma_f32_16x16x32_bf16).
// A rows beyond M must be readable (caller pads allocations).
// act: 0 none, 1 tanh, 2 sigmoid.  Output to Cf (fp32) and/or Cb (bf16).
// ---------------------------------------------------------------------------
__global__ __launch_bounds__(256) void gemm_bf16(
    const ushort* __restrict__ A, const ushort* __restrict__ BT,
    float* __restrict__ Cf, ushort* __restrict__ Cb,
    const float* __restrict__ bias, const float* __restrict__ addsrc,
    int M, int K, int Nc, int act)
{
    int w = threadIdx.x >> 6, lane = threadIdx.x & 63;
    int quad = lane >> 4, l16 = lane & 15;
    int m0 = blockIdx.y * 128 + w * 32;
    int n0 = blockIdx.x * 64;
    f32x4 zf = {0.f, 0.f, 0.f, 0.f};
    f32x4 acc[2][4];
    #pragma unroll
    for (int rt = 0; rt < 2; ++rt)
        #pragma unroll
        for (int ct = 0; ct < 4; ++ct) acc[rt][ct] = zf;

    for (int k0 = 0; k0 < K; k0 += 32) {
        int kk = k0 + quad * 8;
        bf16x8 a0 = *(const bf16x8*)(A + (size_t)(m0 + l16) * K + kk);
        bf16x8 a1 = *(const bf16x8*)(A + (size_t)(m0 + 16 + l16) * K + kk);
        bf16x8 b[4];
        #pragma unroll
        for (int ct = 0; ct < 4; ++ct)
            b[ct] = *(const bf16x8*)(BT + (size_t)(n0 + ct * 16 + l16) * K + kk);
        #pragma unroll
        for (int ct = 0; ct < 4; ++ct) {
            acc[0][ct] = __builtin_amdgcn_mfma_f32_16x16x32_bf16(a0, b[ct], acc[0][ct], 0, 0, 0);
            acc[1][ct] = __builtin_amdgcn_mfma_f32_16x16x32_bf16(a1, b[ct], acc[1][ct], 0, 0, 0);
        }
    }

    #pragma unroll
    for (int rt = 0; rt < 2; ++rt) {
        int ibase = m0 + rt * 16 + quad * 4;
        #pragma unroll
        for (int r = 0; r < 4; ++r) {
            int i = ibase + r;
            if (i >= M) continue;
            #pragma unroll
            for (int ct = 0; ct < 4; ++ct) {
                int j = n0 + ct * 16 + l16;
                float v = acc[rt][ct][r];
                if (bias)   v += bias[j];
                if (addsrc) v += addsrc[(size_t)i * Nc + j];
                if (act == 1)      v = fast_tanh(v);
                else if (act == 2) v = fast_sigmoid(v);
                if (Cf) Cf[(size_t)i * Nc + j] = v;
                if (Cb) Cb[(size_t)i * Nc + j] = f2bf(v);
            }
        }
    }
}

// ---------------------------------------------------------------------------
// Per-node attention dots (bf16 h). One wave per row.
// ---------------------------------------------------------------------------
__global__ __launch_bounds__(256) void att_vec128(
    const ushort* __restrict__ h, const float* __restrict__ a_src,
    const float* __restrict__ a_dst, float* __restrict__ as_out,
    float* __restrict__ ad_out, int rows)
{
    int wid  = (blockIdx.x * 256 + threadIdx.x) >> 6;
    int lane = threadIdx.x & 63;
    if (wid >= rows) return;
    const ushort* hr = h + (size_t)wid * 128;
    float v0 = bf2f(hr[lane]), v1 = bf2f(hr[64 + lane]);
    float pa0 = v0 * a_src[lane], pa1 = v1 * a_src[64 + lane];
    float pd0 = v0 * a_dst[lane], pd1 = v1 * a_dst[64 + lane];
    #pragma unroll
    for (int m = 1; m <= 16; m <<= 1) {
        pa0 += __shfl_xor(pa0, m); pa1 += __shfl_xor(pa1, m);
        pd0 += __shfl_xor(pd0, m); pd1 += __shfl_xor(pd1, m);
    }
    if ((lane & 31) == 0) {
        int g = lane >> 5;
        as_out[wid * 4 + g] = pa0; as_out[wid * 4 + 2 + g] = pa1;
        ad_out[wid * 4 + g] = pd0; ad_out[wid * 4 + 2 + g] = pd1;
    }
}

__global__ __launch_bounds__(256) void att_vec64(
    const ushort* __restrict__ h, const float* __restrict__ a_src,
    const float* __restrict__ a_dst, float* __restrict__ as_out,
    float* __restrict__ ad_out, int rows)
{
    int wid  = (blockIdx.x * 256 + threadIdx.x) >> 6;
    int lane = threadIdx.x & 63;
    if (wid >= rows) return;
    float v = bf2f(h[(size_t)wid * 64 + lane]);
    float pa = v * a_src[lane], pd = v * a_dst[lane];
    #pragma unroll
    for (int m = 1; m <= 8; m <<= 1) { pa += __shfl_xor(pa, m); pd += __shfl_xor(pd, m); }
    if ((lane & 15) == 0) {
        int g = lane >> 4;
        as_out[wid * 4 + g] = pa; ad_out[wid * 4 + g] = pd;
    }
}

// ---------------------------------------------------------------------------
// CSR build over dst
// ---------------------------------------------------------------------------
__global__ void count_edges(const int* __restrict__ eidx, int* __restrict__ counts)
{
    int idx = blockIdx.x * 256 + threadIdx.x;
    if (idx >= TE_) return;
    int t = idx / E_, e = idx - t * E_;
    int d = eidx[(size_t)t * 2 * E_ + E_ + e];
    atomicAdd(&counts[t * N_ + d], 1);
}

__global__ __launch_bounds__(1024) void scan_per_t(
    const int* __restrict__ counts, int* __restrict__ rowptr, int* __restrict__ cursor)
{
    const int CH = 10;
    int t = blockIdx.x, i = threadIdx.x;
    int base0 = t * N_;
    int cnt[CH];
    int s = 0;
    int g0 = i * CH;
    #pragma unroll
    for (int q = 0; q < CH; ++q) {
        int g = g0 + q;
        cnt[q] = (g < N_) ? counts[base0 + g] : 0;
        s += cnt[q];
    }
    __shared__ int buf[1024];
    buf[i] = s;
    __syncthreads();
    for (int off = 1; off < 1024; off <<= 1) {
        int v = (i >= off) ? buf[i - off] : 0;
        __syncthreads();
        buf[i] += v;
        __syncthreads();
    }
    int run = t * E_ + buf[i] - s;
    #pragma unroll
    for (int q = 0; q < CH; ++q) {
        int g = g0 + q;
        if (g < N_) {
            rowptr[base0 + g] = run;
            cursor[base0 + g] = run;
            run += cnt[q];
        }
    }
    if (t == T_ - 1 && i == 1023) rowptr[T_ * N_] = TE_;
}

__global__ void fill_csr(const int* __restrict__ eidx, const float* __restrict__ ew,
                         int* __restrict__ cursor, int* __restrict__ src_csr,
                         float* __restrict__ ew_csr)
{
    int idx = blockIdx.x * 256 + threadIdx.x;
    if (idx >= TE_) return;
    int t = idx / E_, e = idx - t * E_;
    int s = eidx[(size_t)t * 2 * E_ + e];
    int d = eidx[(size_t)t * 2 * E_ + E_ + e];
    float w = ew[(size_t)t * E_ + e];
    int pos = atomicAdd(&cursor[t * N_ + d], 1);
    src_csr[pos] = t * N_ + s;
    ew_csr[pos] = w;
}

// ---------------------------------------------------------------------------
// GAT aggregation (single pass: softmax max-shift cancels exactly in num/den
// and exp args are bounded ~|0.5|, so no overflow). bf16 h in, bf16 out.
// ---------------------------------------------------------------------------
__global__ __launch_bounds__(256) void gat_node_128(
    const ushort* __restrict__ h, const float* __restrict__ as,
    const float* __restrict__ ad, const int* __restrict__ rowptr,
    const int* __restrict__ src_csr, const float* __restrict__ ew_csr,
    ushort* __restrict__ outp, int rows)
{
    int wid  = (blockIdx.x * 256 + threadIdx.x) >> 6;
    int lane = threadIdx.x & 63;
    if (wid >= rows) return;
    int start = rowptr[wid], end = rowptr[wid + 1];
    int h0 = lane >> 5, h1 = 2 + h0;
    float ad0 = ad[wid * 4 + h0], ad1 = ad[wid * 4 + h1];
    float acc0 = 0.f, acc1 = 0.f, den0 = 0.f, den1 = 0.f;
    for (int p = start; p < end; ++p) {
        int s = src_csr[p];
        float w = ew_csr[p];
        float e0 = as[s * 4 + h0] + ad0; e0 = e0 > 0.f ? e0 : 0.2f * e0;
        float e1 = as[s * 4 + h1] + ad1; e1 = e1 > 0.f ? e1 : 0.2f * e1;
        float x0 = __expf(e0) * w;
        float x1 = __expf(e1) * w;
        den0 += x0; den1 += x1;
        const ushort* hs = h + (size_t)s * 128;
        acc0 += x0 * bf2f(hs[lane]);
        acc1 += x1 * bf2f(hs[64 + lane]);
    }
    float o0 = acc0 / (den0 + 1e-16f);
    float o1 = acc1 / (den1 + 1e-16f);
    o0 = o0 > 0.f ? o0 : (__expf(o0) - 1.f);
    o1 = o1 > 0.f ? o1 : (__expf(o1) - 1.f);
    outp[(size_t)wid * 128 + lane]      = f2bf(o0);
    outp[(size_t)wid * 128 + 64 + lane] = f2bf(o1);
}

__global__ __launch_bounds__(256) void gat_node_64(
    const ushort* __restrict__ h, const float* __restrict__ as,
    const float* __restrict__ ad, const int* __restrict__ rowptr,
    const int* __restrict__ src_csr, const float* __restrict__ ew_csr,
    ushort* __restrict__ outp, int rows)
{
    int wid  = (blockIdx.x * 256 + threadIdx.x) >> 6;
    int lane = threadIdx.x & 63;
    if (wid >= rows) return;
    int start = rowptr[wid], end = rowptr[wid + 1];
    int hh = lane >> 4;
    float adv = ad[wid * 4 + hh];
    float acc = 0.f, den = 0.f;
    for (int p = start; p < end; ++p) {
        int s = src_csr[p];
        float w = ew_csr[p];
        float e = as[s * 4 + hh] + adv; e = e > 0.f ? e : 0.2f * e;
        float x = __expf(e) * w;
        den += x;
        acc += x * bf2f(h[(size_t)s * 64 + lane]);
    }
    float o = acc / (den + 1e-16f);
    o = o > 0.f ? o : (__expf(o) - 1.f);
    outp[(size_t)wid * 64 + lane] = f2bf(o);
}

// ---------------------------------------------------------------------------
// Meso pooling + agg assembly (g2 in bf16, agg out bf16)
// ---------------------------------------------------------------------------
__global__ __launch_bounds__(256) void meso_acc(
    const ushort* __restrict__ g2, const int* __restrict__ part,
    const float* __restrict__ Dw, float* __restrict__ msum, float* __restrict__ mden)
{
    int wid  = (blockIdx.x * 256 + threadIdx.x) >> 6;
    int lane = threadIdx.x & 63;
    if (wid >= TN_) return;
    int t = wid / N_;
    int p = part[wid];
    float dv = Dw[wid];
    atomicAdd(&msum[((size_t)(t * NC_ + p) << 6) + lane], dv * bf2f(g2[(size_t)wid * 64 + lane]));
    if (lane == 0) atomicAdd(&mden[t * NC_ + p], dv);
}

__global__ void agg_assemble(
    const ushort* __restrict__ g2, const int* __restrict__ part,
    const float* __restrict__ msum, const float* __restrict__ mden,
    ushort* __restrict__ agg)
{
    int idx = blockIdx.x * 256 + threadIdx.x;   // < TN*128
    int row = idx >> 7, d = idx & 127;
    ushort v;
    if (d < 64) {
        v = g2[(size_t)row * 64 + d];
    } else {
        int t = row / N_;
        int p = part[row];
        v = f2bf(msum[((size_t)(t * NC_ + p) << 6) + (d - 64)] / (mden[t * NC_ + p] + 1e-16f));
    }
    agg[idx] = v;
}

// ---------------------------------------------------------------------------
// LSTM cell: z (N x 512 fp32), c fp32 in-place, h out bf16 (row stride 128)
// ---------------------------------------------------------------------------
__global__ void lstm_cell(const float* __restrict__ z, float* __restrict__ c,
                          ushort* __restrict__ hb)
{
    int idx = blockIdx.x * 256 + threadIdx.x;   // < N*128
    int n = idx >> 7, j = idx & 127;
    const float* zr = z + (size_t)n * 512;
    float zi = zr[j], zf = zr[128 + j], zg = zr[256 + j], zo = zr[384 + j];
    float si = fast_sigmoid(zi);
    float sf = fast_sigmoid(zf);
    float so = fast_sigmoid(zo);
    float cn = sf * c[idx] + si * fast_tanh(zg);
    c[idx] = cn;
    hb[(size_t)n * 128 + j] = f2bf(so * fast_tanh(cn));
}

// ---------------------------------------------------------------------------
// Column sum-of-squares for emb (fp32), then normalize -> bf16 + per-row sq
// ---------------------------------------------------------------------------
__global__ __launch_bounds__(256) void col_sumsq(const float* __restrict__ emb,
                                                 float* __restrict__ colss)
{
    int tid = threadIdx.x;
    int col = tid & 63, rq = tid >> 6;
    float s = 0.f;
    for (int r = blockIdx.x * 4 + rq; r < N_; r += 40 * 4) {
        float v = emb[(size_t)r * 64 + col];
        s += v * v;
    }
    __shared__ float red[256];
    red[tid] = s;
    __syncthreads();
    if (tid < 64)
        atomicAdd(&colss[tid], red[tid] + red[tid + 64] + red[tid + 128] + red[tid + 192]);
}

// sq computed from the bf16-ROUNDED values so the i==j cancellation in the
// final dist is exact.
__global__ __launch_bounds__(256) void norm_rows(const float* __restrict__ emb,
                                                 const float* __restrict__ colss,
                                                 ushort* __restrict__ embb,
                                                 float* __restrict__ sq, int rows)
{
    int wid  = (blockIdx.x * 256 + threadIdx.x) >> 6;
    int lane = threadIdx.x & 63;
    if (wid >= rows) return;
    float nv = emb[(size_t)wid * 64 + lane] / sqrtf(colss[lane]);
    ushort ub = f2bf(nv);
    embb[(size_t)wid * 64 + lane] = ub;
    float nq = bf2f(ub);
    float q = nq * nq;
    #pragma unroll
    for (int m = 1; m <= 32; m <<= 1) q += __shfl_xor(q, m);
    if (lane == 0) sq[wid] = q;
}

// ---------------------------------------------------------------------------
// Fused final, MFMA: S = scal.scal^T, G = emb.emb^T (K=64, bf16),
// out = 1 + tanh((2G - sq_i - sq_j) * S). Block 128x128 (4 waves, 64x64 each).
// Nontemporal stores to kill the RFO fetch seen in round 1.
// emb/scal/sq padded to NPAD_ rows (poison pad = tiny denormals, stores guarded).
// ---------------------------------------------------------------------------
__global__ __launch_bounds__(256) void final_adj_mfma(
    const ushort* __restrict__ embb, const ushort* __restrict__ scalb,
    const float* __restrict__ sq, float* __restrict__ outp)
{
    int w = threadIdx.x >> 6, lane = threadIdx.x & 63;
    int quad = lane >> 4, l16 = lane & 15;
    int bi = blockIdx.y * 128 + (w >> 1) * 64;
    int bj = blockIdx.x * 128 + (w & 1) * 64;
    f32x4 zf = {0.f, 0.f, 0.f, 0.f};
    f32x4 accS[4][4], accG[4][4];
    #pragma unroll
    for (int rt = 0; rt < 4; ++rt)
        #pragma unroll
        for (int ct = 0; ct < 4; ++ct) { accS[rt][ct] = zf; accG[rt][ct] = zf; }

    #pragma unroll
    for (int ks = 0; ks < 2; ++ks) {
        int k0 = ks * 32 + quad * 8;
        bf16x8 ae[4], af[4], be[4], bs[4];
        #pragma unroll
        for (int t = 0; t < 4; ++t) {
            int ri = bi + t * 16 + l16;
            int rj = bj + t * 16 + l16;
            ae[t] = *(const bf16x8*)(embb  + (size_t)ri * 64 + k0);
            af[t] = *(const bf16x8*)(scalb + (size_t)ri * 64 + k0);
            be[t] = *(const bf16x8*)(embb  + (size_t)rj * 64 + k0);
            bs[t] = *(const bf16x8*)(scalb + (size_t)rj * 64 + k0);
        }
        #pragma unroll
        for (int rt = 0; rt < 4; ++rt)
            #pragma unroll
            for (int ct = 0; ct < 4; ++ct) {
                accG[rt][ct] = __builtin_amdgcn_mfma_f32_16x16x32_bf16(ae[rt], be[ct], accG[rt][ct], 0, 0, 0);
                accS[rt][ct] = __builtin_amdgcn_mfma_f32_16x16x32_bf16(af[rt], bs[ct], accS[rt][ct], 0, 0, 0);
            }
    }

    float sqj[4];
    #pragma unroll
    for (int ct = 0; ct < 4; ++ct) sqj[ct] = sq[bj + ct * 16 + l16];
    #pragma unroll
    for (int rt = 0; rt < 4; ++rt) {
        int ibase = bi + rt * 16 + quad * 4;
        #pragma unroll
        for (int r = 0; r < 4; ++r) {
            int i = ibase + r;
            if (i >= N_) continue;
            float sqi = sq[i];
            #pragma unroll
            for (int ct = 0; ct < 4; ++ct) {
                int j = bj + ct * 16 + l16;
                if (j >= N_) continue;
                float G = accG[rt][ct][r], S = accS[rt][ct][r];
                float dist = 2.f * G - sqi - sqj[ct];
                // 1 + tanh(y) = 2 - 2/(e^{2y}+1), inf-safe
                float t = __expf(2.f * dist * S);
                float v = 2.f - 2.f / (t + 1.f);
                __builtin_nontemporal_store(v, outp + (size_t)i * N_ + j);
            }
        }
    }
}

// ---------------------------------------------------------------------------
extern "C" void kernel_launch(void* const* d_in, const int* in_sizes, int n_in,
                              void* d_out, int out_size, void* d_ws, size_t ws_size,
                              hipStream_t stream)
{
    (void)in_sizes; (void)n_in; (void)out_size; (void)ws_size;
    const float* feat    = (const float*)d_in[0];
    const float* eweight = (const float*)d_in[1];
    const float* Dw      = (const float*)d_in[2];
    const float* W1      = (const float*)d_in[3];
    const float* a_src1  = (const float*)d_in[4];
    const float* a_dst1  = (const float*)d_in[5];
    const float* W2      = (const float*)d_in[6];
    const float* a_src2  = (const float*)d_in[7];
    const float* a_dst2  = (const float*)d_in[8];
    const float* Wx      = (const float*)d_in[9];
    const float* Wh      = (const float*)d_in[10];
    const float* b_lstm  = (const float*)d_in[11];
    const float* emb_W   = (const float*)d_in[12];
    const float* emb_b   = (const float*)d_in[13];
    const float* scal_W  = (const float*)d_in[14];
    const float* scal_b  = (const float*)d_in[15];
    const int*   eidx    = (const int*)d_in[16];
    const int*   part    = (const int*)d_in[17];

    // ---- scratch layout (floats) inside d_out (dead before final_adj) ----
    float* out = (float*)d_out;
    ushort* h1b   = (ushort*)(out + 0);          // 80000x128 bf16 (5,120,000 f)
    ushort* g1b   = (ushort*)(out + 5120000);    // 80000x128 bf16
    ushort* h2b   = (ushort*)(out + 10240000);   // 80000x64 bf16
    ushort* g2b   = (ushort*)(out + 12800000);   // 80000x64 bf16
    float* as1    = out + 15360000;              // TN*4
    float* ad1    = out + 15680000;
    float* as2    = out + 16000000;
    float* ad2    = out + 16320000;
    int*   rowptr = (int*)(out + 16640000);      // TN+1
    int*   cursor = (int*)(out + 16720064);
    int*   counts = (int*)(out + 16800064);
    int*   src_csr= (int*)(out + 16880064);      // TE
    float* ew_csr = out + 19440064;              // TE
    float* msum   = out + 22000064;              // T*100*64
    float* mden   = out + 22051264;              // T*100
    ushort* aggb  = (ushort*)(out + 22052064);   // 80000x128 bf16
    float* ZX     = out + 27172064;              // 80000x512 fp32
    float* zbuf   = out + 68132064;              // 10000x512 fp32
    float* cstate = out + 73252064;              // 10000x128 fp32
    ushort* hbf   = (ushort*)(out + 74532064);   // NPAD x128 bf16 (647,168 f)
    ushort* featb = (ushort*)(out + 75179232);   // 80000x128 bf16
    ushort* W1T   = (ushort*)(out + 80299232);   // 128x128
    ushort* W2T   = (ushort*)(out + 80307424);   // 64x128
    ushort* WxT   = (ushort*)(out + 80311520);   // 512x128
    ushort* WhT   = (ushort*)(out + 80344288);   // 512x128
    ushort* eWT   = (ushort*)(out + 80377056);   // 64x128
    ushort* sWT   = (ushort*)(out + 80381152);   // 64x128
    float* embf   = out + 80385248;              // 10000x64 fp32
    float* colss  = out + 81025248;              // 64

    // ---- live-at-final buffers in d_ws ----
    ushort* embb  = (ushort*)d_ws;               // NPAD x 64 bf16
    ushort* scalb = embb + (size_t)NPAD_ * 64;   // NPAD x 64 bf16
    float*  sq    = (float*)(scalb + (size_t)NPAD_ * 64);  // NPAD fp32

    // ---- zero-init accumulation targets ----
    hipMemsetAsync(counts, 0, TN_ * sizeof(int), stream);
    hipMemsetAsync(msum, 0, (T_ * NC_ * 64 + T_ * NC_) * sizeof(float), stream);
    hipMemsetAsync(cstate, 0, (size_t)N_ * DR_ * sizeof(float), stream);
    hipMemsetAsync(hbf, 0, (size_t)NPAD_ * DR_ * sizeof(ushort), stream);  // h0 = 0 (+pad)
    hipMemsetAsync(colss, 0, 64 * sizeof(float), stream);

    // ---- converts ----
    conv_feat<<<5000, 256, 0, stream>>>(feat, featb, TN_ * F_ / 8);
    conv_weights<<<672, 256, 0, stream>>>(W1, W2, Wx, Wh, emb_W, scal_W,
                                          W1T, W2T, WxT, WhT, eWT, sWT);

    // ---- GAT layer 1 (batched over T) ----
    gemm_bf16<<<dim3(2, 625), 256, 0, stream>>>(featb, W1T, nullptr, h1b, nullptr, nullptr, TN_, 128, 128, 0);
    att_vec128<<<TN_/4, 256, 0, stream>>>(h1b, a_src1, a_dst1, as1, ad1, TN_);
    count_edges<<<(TE_+255)/256, 256, 0, stream>>>(eidx, counts);
    scan_per_t<<<T_, 1024, 0, stream>>>(counts, rowptr, cursor);
    fill_csr<<<(TE_+255)/256, 256, 0, stream>>>(eidx, eweight, cursor, src_csr, ew_csr);
    gat_node_128<<<TN_/4, 256, 0, stream>>>(h1b, as1, ad1, rowptr, src_csr, ew_csr, g1b, TN_);

    // ---- GAT layer 2 ----
    gemm_bf16<<<dim3(1, 625), 256, 0, stream>>>(g1b, W2T, nullptr, h2b, nullptr, nullptr, TN_, 128, 64, 0);
    att_vec64<<<TN_/4, 256, 0, stream>>>(h2b, a_src2, a_dst2, as2, ad2, TN_);
    gat_node_64<<<TN_/4, 256, 0, stream>>>(h2b, as2, ad2, rowptr, src_csr, ew_csr, g2b, TN_);

    // ---- meso + agg ----
    meso_acc<<<TN_/4, 256, 0, stream>>>(g2b, part, Dw, msum, mden);
    agg_assemble<<<TN_*128/256, 256, 0, stream>>>(g2b, part, msum, mden, aggb);

    // ---- LSTM: batched input projection, then 8-step recurrence ----
    gemm_bf16<<<dim3(8, 625), 256, 0, stream>>>(aggb, WxT, ZX, nullptr, b_lstm, nullptr, TN_, 128, 512, 0);
    for (int t = 0; t < T_; ++t) {
        gemm_bf16<<<dim3(8, 79), 256, 0, stream>>>(hbf, WhT, zbuf, nullptr, nullptr,
                                                   ZX + (size_t)t * N_ * 512, N_, 128, 512, 0);
        lstm_cell<<<N_*DR_/256, 256, 0, stream>>>(zbuf, cstate, hbf);
    }

    // ---- decoder heads ----
    gemm_bf16<<<dim3(1, 79), 256, 0, stream>>>(hbf, eWT, embf, nullptr, emb_b, nullptr, N_, 128, 64, 1);
    gemm_bf16<<<dim3(1, 79), 256, 0, stream>>>(hbf, sWT, nullptr, scalb, scal_b, nullptr, N_, 128, 64, 2);
    col_sumsq<<<40, 256, 0, stream>>>(embf, colss);
    norm_rows<<<(N_+3)/4, 256, 0, stream>>>(embf, colss, embb, sq, N_);

    // ---- fused final ----
    final_adj_mfma<<<dim3(79, 79), 256, 0, stream>>>(embb, scalb, sq, out);
}